// Round 6
// baseline (698.081 us; speedup 1.0000x reference)
//
#include <hip/hip_runtime.h>
#include <hip/hip_bf16.h>

// CGConv fused for MI355X (gfx950) — round 6: fused atomic aggregation.
// R2->R3 showed the 76.8M fp32 atomics were fully hidden under gemm's latency
// stalls (515us with AND without them). The CSR detour (msg 150MB + sort chain
// + divergent aggregate ~ 352us) only existed to avoid them. This round:
// R5's fast gemm (bf16 h-table, mt=2, B-frag reuse) + unsafeAtomicAdd epilogue
// directly into fp32 hnew. Pipeline: memset, cvt_h, pack_w, gemm_atomic,
// finalize. 5 launches, no 150MB round-trip.

#define NODE_DIM 96
#define EDGE_DIM 64
#define IN_DIM   256
#define NT_TILES 12       // 192 output cols = 96 gates + 96 msgs
#define KT_TILES 8        // 256 / 32

typedef float  f32x4  __attribute__((ext_vector_type(4)));
typedef __bf16 bf16x8 __attribute__((ext_vector_type(8)));

__device__ __forceinline__ unsigned short bf16rne(float f) {
    unsigned int u = __float_as_uint(f);
    u += 0x7FFFu + ((u >> 16) & 1u);
    return (unsigned short)(u >> 16);
}

// ---------------------------------------------------------------------------
// Pack W_e/W_n (256x96 fp32 row-major) into bf16 MFMA B-fragment order.
// tile (kt,nt), lane l, j -> W[kt*32+(l>>4)*8+j][(nt%6)*16+(l&15)], nt<6:We else Wn
// ---------------------------------------------------------------------------
__global__ void pack_w_kernel(const float* __restrict__ We,
                              const float* __restrict__ Wn,
                              unsigned short* __restrict__ bpack) {
    int t = blockIdx.x * blockDim.x + threadIdx.x;
    if (t >= KT_TILES * NT_TILES * 64) return;
    int tile = t >> 6, lane = t & 63;
    int kt = tile / NT_TILES, nt = tile % NT_TILES;
    const float* W = (nt < 6) ? We : Wn;
    int n  = (nt % 6) * 16 + (lane & 15);
    int k0 = kt * 32 + (lane >> 4) * 8;
    union { unsigned short u[8]; uint4 v; } tmp;
#pragma unroll
    for (int j = 0; j < 8; ++j) tmp.u[j] = bf16rne(W[(k0 + j) * NODE_DIM + n]);
    *(uint4*)(bpack + (size_t)t * 8) = tmp.v;
}

// ---------------------------------------------------------------------------
// h (N x 96 fp32) -> hb (N x 96 bf16)
// ---------------------------------------------------------------------------
__global__ void cvt_h_kernel(const float* __restrict__ h,
                             unsigned short* __restrict__ hb, int total8) {
    int i = blockIdx.x * 256 + threadIdx.x;
    if (i >= total8) return;
    const float4 v0 = ((const float4*)h)[i * 2];
    const float4 v1 = ((const float4*)h)[i * 2 + 1];
    union { unsigned short u[8]; uint4 v; } p;
    p.u[0] = bf16rne(v0.x); p.u[1] = bf16rne(v0.y);
    p.u[2] = bf16rne(v0.z); p.u[3] = bf16rne(v0.w);
    p.u[4] = bf16rne(v1.x); p.u[5] = bf16rne(v1.y);
    p.u[6] = bf16rne(v1.z); p.u[7] = bf16rne(v1.w);
    ((uint4*)hb)[i] = p.v;
}

// ---------------------------------------------------------------------------
// Fused GEMM + activation + atomic scatter-add.
// Block = 256 = 4 waves; wave handles 32 edges (mt=2). No LDS, no barriers.
// ---------------------------------------------------------------------------
__global__ __launch_bounds__(256, 3)
void gemm_atomic_kernel(const unsigned short* __restrict__ hb,
                        const int*   __restrict__ eidx,
                        const float* __restrict__ ea,
                        const unsigned short* __restrict__ bpack,
                        const float* __restrict__ be,
                        const float* __restrict__ bn,
                        float* __restrict__ hnew,
                        float* __restrict__ cnt,
                        int E) {
    const int tid  = threadIdx.x;
    const int wave = tid >> 6, lane = tid & 63;
    const int m    = lane & 15;
    const int quad = lane >> 4;
    const int base = blockIdx.x * 128 + wave * 32;

    const unsigned short* hsq[2];
    const unsigned short* hdq[2];
    const float*          epq[2];
    int dstv[2];
#pragma unroll
    for (int mt = 0; mt < 2; ++mt) {
        int e  = base + mt * 16 + m;
        int eg = (e < E) ? e : (E - 1);
        int src = eidx[eg];
        int dst = eidx[E + eg];
        dstv[mt] = dst;
        hsq[mt] = hb + (size_t)src * NODE_DIM + quad * 8;
        hdq[mt] = hb + (size_t)dst * NODE_DIM + quad * 8;
        epq[mt] = ea + (size_t)eg  * EDGE_DIM + quad * 8;
        if (quad == 0 && e < E) unsafeAtomicAdd(cnt + dst, 1.0f);
    }
    const unsigned short* bl = bpack + lane * 8;

    f32x4 acc[2][NT_TILES];
#pragma unroll
    for (int mt = 0; mt < 2; ++mt)
#pragma unroll
        for (int nt = 0; nt < NT_TILES; ++nt) acc[mt][nt] = (f32x4){0.f, 0.f, 0.f, 0.f};

#pragma unroll
    for (int kt = 0; kt < KT_TILES; ++kt) {
        bf16x8 A[2];
#pragma unroll
        for (int mt = 0; mt < 2; ++mt) {
            if (kt < 3) {
                A[mt] = *(const bf16x8*)(hsq[mt] + kt * 32);
            } else if (kt < 6) {
                A[mt] = *(const bf16x8*)(hdq[mt] + (kt - 3) * 32);
            } else {
                const float4 v0 = *(const float4*)(epq[mt] + (kt - 6) * 32);
                const float4 v1 = *(const float4*)(epq[mt] + (kt - 6) * 32 + 4);
                union { unsigned short u[8]; bf16x8 b; } t;
                t.u[0] = bf16rne(v0.x); t.u[1] = bf16rne(v0.y);
                t.u[2] = bf16rne(v0.z); t.u[3] = bf16rne(v0.w);
                t.u[4] = bf16rne(v1.x); t.u[5] = bf16rne(v1.y);
                t.u[6] = bf16rne(v1.z); t.u[7] = bf16rne(v1.w);
                A[mt] = t.b;
            }
        }
#pragma unroll
        for (int nt = 0; nt < NT_TILES; ++nt) {
            bf16x8 bfrag = *(const bf16x8*)(bl + (kt * NT_TILES + nt) * 512);
            acc[0][nt] = __builtin_amdgcn_mfma_f32_16x16x32_bf16(A[0], bfrag, acc[0][nt], 0, 0, 0);
            acc[1][nt] = __builtin_amdgcn_mfma_f32_16x16x32_bf16(A[1], bfrag, acc[1][nt], 0, 0, 0);
        }
    }

    // epilogue: C layout col = nt*16 + m, row-in-tile = quad*4 + r.
    // Row ee's dst lives in lane (quad*4 + r) of quad 0 -> shfl broadcast.
#pragma unroll
    for (int mt = 0; mt < 2; ++mt) {
#pragma unroll
        for (int r = 0; r < 4; ++r) {
            const int ee = base + mt * 16 + quad * 4 + r;
            const int d  = __shfl(dstv[mt], quad * 4 + r, 64);
            if (ee >= E) continue;
            float* hrow = hnew + (size_t)d * NODE_DIM;
#pragma unroll
            for (int nt = 0; nt < 6; ++nt) {
                const int col = nt * 16 + m;
                float g  = acc[mt][nt][r]     + be[col];
                float mm = acc[mt][nt + 6][r] + bn[col];
                float gate = 1.0f / (1.0f + __expf(-g));
                float sp   = fmaxf(mm, 0.0f) + __logf(1.0f + __expf(-fabsf(mm)));
                unsafeAtomicAdd(hrow + col, gate * sp);
            }
        }
    }
}

// ---------------------------------------------------------------------------
// finalize: out = h + hnew / max(cnt,1)
// ---------------------------------------------------------------------------
__global__ void finalize_kernel(const float* __restrict__ h,
                                const float* __restrict__ hnew,
                                const float* __restrict__ cnt,
                                float* __restrict__ out,
                                int total4) {
    int i = blockIdx.x * blockDim.x + threadIdx.x;
    if (i >= total4) return;
    int n = i / 24;
    float inv = 1.0f / fmaxf(cnt[n], 1.0f);
    float4 hv = ((const float4*)h)[i];
    float4 av = ((const float4*)hnew)[i];
    float4 o = {hv.x + av.x * inv, hv.y + av.y * inv, hv.z + av.z * inv, hv.w + av.w * inv};
    ((float4*)out)[i] = o;
}

// ---------------------------------------------------------------------------
extern "C" void kernel_launch(void* const* d_in, const int* in_sizes, int n_in,
                              void* d_out, int out_size, void* d_ws, size_t ws_size,
                              hipStream_t stream) {
    const float* h   = (const float*)d_in[0];
    const int*   ei  = (const int*)  d_in[1];
    const float* ea  = (const float*)d_in[2];
    const float* We  = (const float*)d_in[3];
    const float* be  = (const float*)d_in[4];
    const float* Wn  = (const float*)d_in[5];
    const float* bn  = (const float*)d_in[6];

    const int N = in_sizes[0] / NODE_DIM;     // 50000
    const int E = in_sizes[2] / EDGE_DIM;     // 800000
    char* ws = (char*)d_ws;

    size_t off = 0;
    auto take = [&](size_t bytes) { size_t o = off; off = (off + bytes + 511) & ~(size_t)511; return o; };
    const size_t O_BPACK = take((size_t)KT_TILES * NT_TILES * 64 * 16);   // 96 KB
    const size_t O_CNT   = take((size_t)N * 4);                           // 200 KB
    const size_t O_HNEW  = take((size_t)N * NODE_DIM * 4);                // 19.2 MB
    const size_t O_HB    = take((size_t)N * NODE_DIM * 2);                // 9.6 MB
    (void)ws_size;

    unsigned short* bpack = (unsigned short*)(ws + O_BPACK);
    float* cnt  = (float*)(ws + O_CNT);
    float* hnew = (float*)(ws + O_HNEW);
    unsigned short* hb = (unsigned short*)(ws + O_HB);

    // zero cnt + hnew (contiguous region; ws poisoned 0xAA before every call)
    hipMemsetAsync(ws + O_CNT, 0, O_HB - O_CNT, stream);

    pack_w_kernel<<<(KT_TILES * NT_TILES * 64 + 255) / 256, 256, 0, stream>>>(We, Wn, bpack);

    const int total8 = N * NODE_DIM / 8;   // 600000
    cvt_h_kernel<<<(total8 + 255) / 256, 256, 0, stream>>>(h, hb, total8);

    gemm_atomic_kernel<<<(E + 127) / 128, 256, 0, stream>>>(hb, ei, ea, bpack, be, bn, hnew, cnt, E);

    const int total4 = N * (NODE_DIM / 4);
    finalize_kernel<<<(total4 + 255) / 256, 256, 0, stream>>>(h, hnew, cnt, (float*)d_out, total4);
}

// Round 7
// 645.653 us; speedup vs baseline: 1.0812x; 1.0812x over previous
//
#include <hip/hip_runtime.h>
#include <hip/hip_bf16.h>

// CGConv fused for MI355X (gfx950) — round 7: dst-sorted fused gemm.
// Pipeline: pack_w, cvt_h, CSR sort (hist/scan/scatter -> ssrc+eid, sdst),
// gemm over SORTED edges with per-lane run-combined unsafeAtomicAdd epilogue,
// finalize (deg from CSR offsets). msg/rank/aggregate deleted.
// Evidence: R6 showed 76.8M scattered atomics cost ~180us exposed; R5 showed
// the CSR aggregate costs ~250us + 300MB round-trip. Sorted order attacks
// both: consecutive rows share dst (combine before atomic, ~23M atomics,
// fewer write-through lines) and h[dst] gathers become L1-hot.

#define NODE_DIM 96
#define EDGE_DIM 64
#define IN_DIM   256
#define NT_TILES 12       // 192 output cols = 96 gates + 96 msgs
#define KT_TILES 8        // 256 / 32

typedef float  f32x4  __attribute__((ext_vector_type(4)));
typedef __bf16 bf16x8 __attribute__((ext_vector_type(8)));

__device__ __forceinline__ unsigned short bf16rne(float f) {
    unsigned int u = __float_as_uint(f);
    u += 0x7FFFu + ((u >> 16) & 1u);
    return (unsigned short)(u >> 16);
}

// ---------------------------------------------------------------------------
// Pack W_e/W_n (256x96 fp32 row-major) into bf16 MFMA B-fragment order.
// ---------------------------------------------------------------------------
__global__ void pack_w_kernel(const float* __restrict__ We,
                              const float* __restrict__ Wn,
                              unsigned short* __restrict__ bpack) {
    int t = blockIdx.x * blockDim.x + threadIdx.x;
    if (t >= KT_TILES * NT_TILES * 64) return;
    int tile = t >> 6, lane = t & 63;
    int kt = tile / NT_TILES, nt = tile % NT_TILES;
    const float* W = (nt < 6) ? We : Wn;
    int n  = (nt % 6) * 16 + (lane & 15);
    int k0 = kt * 32 + (lane >> 4) * 8;
    union { unsigned short u[8]; uint4 v; } tmp;
#pragma unroll
    for (int j = 0; j < 8; ++j) tmp.u[j] = bf16rne(W[(k0 + j) * NODE_DIM + n]);
    *(uint4*)(bpack + (size_t)t * 8) = tmp.v;
}

// ---------------------------------------------------------------------------
// h (N x 96 fp32) -> hb (N x 96 bf16)
// ---------------------------------------------------------------------------
__global__ void cvt_h_kernel(const float* __restrict__ h,
                             unsigned short* __restrict__ hb, int total8) {
    int i = blockIdx.x * 256 + threadIdx.x;
    if (i >= total8) return;
    const float4 v0 = ((const float4*)h)[i * 2];
    const float4 v1 = ((const float4*)h)[i * 2 + 1];
    union { unsigned short u[8]; uint4 v; } p;
    p.u[0] = bf16rne(v0.x); p.u[1] = bf16rne(v0.y);
    p.u[2] = bf16rne(v0.z); p.u[3] = bf16rne(v0.w);
    p.u[4] = bf16rne(v1.x); p.u[5] = bf16rne(v1.y);
    p.u[6] = bf16rne(v1.z); p.u[7] = bf16rne(v1.w);
    ((uint4*)hb)[i] = p.v;
}

// ---------------------------------------------------------------------------
// CSR build: histogram -> exclusive scan -> scatter (sorted src/eid and dst)
// ---------------------------------------------------------------------------
__global__ void hist_kernel(const int* __restrict__ eidx, unsigned* __restrict__ deg, int E) {
    int e = blockIdx.x * 256 + threadIdx.x;
    if (e < E) atomicAdd(deg + eidx[E + e], 1u);
}

__device__ __forceinline__ unsigned block_excl_scan_256(unsigned v, int tid,
                                                        unsigned* wsum, unsigned* wpre,
                                                        unsigned* total) {
    int lane = tid & 63, w = tid >> 6;
    unsigned inc = v;
#pragma unroll
    for (int o = 1; o < 64; o <<= 1) {
        unsigned t = __shfl_up(inc, o, 64);
        if (lane >= o) inc += t;
    }
    if (lane == 63) wsum[w] = inc;
    __syncthreads();
    if (tid == 0) {
        unsigned s = 0;
#pragma unroll
        for (int k = 0; k < 4; ++k) { wpre[k] = s; s += wsum[k]; }
        *total = s;
    }
    __syncthreads();
    return inc - v + wpre[w];
}

__global__ void scan_block_kernel(const unsigned* __restrict__ deg,
                                  unsigned* __restrict__ scanned,
                                  unsigned* __restrict__ blocksum, int N) {
    __shared__ unsigned wsum[4], wpre[4], total;
    int tid = threadIdx.x;
    int i = blockIdx.x * 256 + tid;
    unsigned v = (i < N) ? deg[i] : 0u;
    unsigned excl = block_excl_scan_256(v, tid, wsum, wpre, &total);
    if (i < N) scanned[i] = excl;
    if (tid == 0) blocksum[blockIdx.x] = total;
}

__global__ void scan_sums_kernel(const unsigned* __restrict__ blocksum,
                                 unsigned* __restrict__ blockpref, int NB) {
    __shared__ unsigned wsum[4], wpre[4], total;
    int tid = threadIdx.x;
    unsigned v = (tid < NB) ? blocksum[tid] : 0u;
    unsigned excl = block_excl_scan_256(v, tid, wsum, wpre, &total);
    if (tid < NB) blockpref[tid] = excl;
}

__global__ void scan_finalize_kernel(const unsigned* __restrict__ scanned,
                                     const unsigned* __restrict__ blockpref,
                                     unsigned* __restrict__ offsets,
                                     unsigned* __restrict__ cursor, int N, int E) {
    int i = blockIdx.x * 256 + threadIdx.x;
    if (i < N) {
        unsigned o = scanned[i] + blockpref[i >> 8];
        offsets[i] = o;
        cursor[i]  = o;
    }
    if (i == 0) offsets[N] = (unsigned)E;
}

__global__ void scatter_kernel(const int* __restrict__ eidx,
                               unsigned* __restrict__ cursor,
                               int2* __restrict__ s_se,   // (src, orig edge id)
                               int*  __restrict__ s_d,    // dst
                               int E) {
    int e = blockIdx.x * 256 + threadIdx.x;
    if (e < E) {
        int s = eidx[e];
        int d = eidx[E + e];
        unsigned pos = atomicAdd(cursor + d, 1u);
        s_se[pos] = make_int2(s, e);
        s_d[pos]  = d;
    }
}

// ---------------------------------------------------------------------------
// Fused GEMM + activation + run-combined atomic scatter over SORTED edges.
// Block = 256 = 4 waves; wave handles 32 sorted rows (mt=2). No LDS.
// ---------------------------------------------------------------------------
__global__ __launch_bounds__(256, 3)
void gemm_sorted_kernel(const unsigned short* __restrict__ hb,
                        const int2* __restrict__ s_se,
                        const int*  __restrict__ s_d,
                        const float* __restrict__ ea,
                        const unsigned short* __restrict__ bpack,
                        const float* __restrict__ be,
                        const float* __restrict__ bn,
                        float* __restrict__ hnew,
                        int E) {
    const int tid  = threadIdx.x;
    const int wave = tid >> 6, lane = tid & 63;
    const int m    = lane & 15;
    const int quad = lane >> 4;
    const int base = blockIdx.x * 128 + wave * 32;

    const unsigned short* hsq[2];
    const unsigned short* hdq[2];
    const float*          epq[2];
    int dstv[2];
#pragma unroll
    for (int mt = 0; mt < 2; ++mt) {
        int r  = base + mt * 16 + m;             // sorted row index
        int rg = (r < E) ? r : (E - 1);
        int2 se = s_se[rg];
        int dst = s_d[rg];
        dstv[mt] = dst;
        hsq[mt] = hb + (size_t)se.x * NODE_DIM + quad * 8;
        hdq[mt] = hb + (size_t)dst  * NODE_DIM + quad * 8;   // L1-hot: runs share dst
        epq[mt] = ea + (size_t)se.y * EDGE_DIM + quad * 8;
    }
    const unsigned short* bl = bpack + lane * 8;

    f32x4 acc[2][NT_TILES];
#pragma unroll
    for (int mt = 0; mt < 2; ++mt)
#pragma unroll
        for (int nt = 0; nt < NT_TILES; ++nt) acc[mt][nt] = (f32x4){0.f, 0.f, 0.f, 0.f};

#pragma unroll
    for (int kt = 0; kt < KT_TILES; ++kt) {
        bf16x8 A[2];
#pragma unroll
        for (int mt = 0; mt < 2; ++mt) {
            if (kt < 3) {
                A[mt] = *(const bf16x8*)(hsq[mt] + kt * 32);
            } else if (kt < 6) {
                A[mt] = *(const bf16x8*)(hdq[mt] + (kt - 3) * 32);
            } else {
                const float4 v0 = *(const float4*)(epq[mt] + (kt - 6) * 32);
                const float4 v1 = *(const float4*)(epq[mt] + (kt - 6) * 32 + 4);
                union { unsigned short u[8]; bf16x8 b; } t;
                t.u[0] = bf16rne(v0.x); t.u[1] = bf16rne(v0.y);
                t.u[2] = bf16rne(v0.z); t.u[3] = bf16rne(v0.w);
                t.u[4] = bf16rne(v1.x); t.u[5] = bf16rne(v1.y);
                t.u[6] = bf16rne(v1.z); t.u[7] = bf16rne(v1.w);
                A[mt] = t.b;
            }
        }
#pragma unroll
        for (int nt = 0; nt < NT_TILES; ++nt) {
            bf16x8 bfrag = *(const bf16x8*)(bl + (kt * NT_TILES + nt) * 512);
            acc[0][nt] = __builtin_amdgcn_mfma_f32_16x16x32_bf16(A[0], bfrag, acc[0][nt], 0, 0, 0);
            acc[1][nt] = __builtin_amdgcn_mfma_f32_16x16x32_bf16(A[1], bfrag, acc[1][nt], 0, 0, 0);
        }
    }

    // Epilogue: C layout col = nt*16 + m, row-in-tile = quad*4 + r.
    // Sorted rows: combine runs with equal dst in-register, then one
    // atomicAdd per (segment, col).
#pragma unroll
    for (int mt = 0; mt < 2; ++mt) {
        int dprev = -1;
        float s[6];
#pragma unroll
        for (int r = 0; r < 4; ++r) {
            const int ee = base + mt * 16 + quad * 4 + r;
            const int d  = __shfl(dstv[mt], quad * 4 + r, 64);
            if (ee >= E) continue;
            float v[6];
#pragma unroll
            for (int nt = 0; nt < 6; ++nt) {
                const int col = nt * 16 + m;
                float g  = acc[mt][nt][r]     + be[col];
                float mm = acc[mt][nt + 6][r] + bn[col];
                float gate = 1.0f / (1.0f + __expf(-g));
                float sp   = fmaxf(mm, 0.0f) + __logf(1.0f + __expf(-fabsf(mm)));
                v[nt] = gate * sp;
            }
            if (d != dprev) {
                if (dprev >= 0) {
                    float* hrow = hnew + (size_t)dprev * NODE_DIM + m;
#pragma unroll
                    for (int nt = 0; nt < 6; ++nt) unsafeAtomicAdd(hrow + nt * 16, s[nt]);
                }
#pragma unroll
                for (int nt = 0; nt < 6; ++nt) s[nt] = v[nt];
                dprev = d;
            } else {
#pragma unroll
                for (int nt = 0; nt < 6; ++nt) s[nt] += v[nt];
            }
        }
        if (dprev >= 0) {
            float* hrow = hnew + (size_t)dprev * NODE_DIM + m;
#pragma unroll
            for (int nt = 0; nt < 6; ++nt) unsafeAtomicAdd(hrow + nt * 16, s[nt]);
        }
    }
}

// ---------------------------------------------------------------------------
// finalize: out = h + hnew / max(deg,1), deg from CSR offsets
// ---------------------------------------------------------------------------
__global__ void finalize_kernel(const float* __restrict__ h,
                                const float* __restrict__ hnew,
                                const unsigned* __restrict__ offsets,
                                float* __restrict__ out,
                                int total4) {
    int i = blockIdx.x * blockDim.x + threadIdx.x;
    if (i >= total4) return;
    int n = i / 24;
    unsigned deg = offsets[n + 1] - offsets[n];
    float inv = 1.0f / (float)(deg > 0u ? deg : 1u);
    float4 hv = ((const float4*)h)[i];
    float4 av = ((const float4*)hnew)[i];
    float4 o = {hv.x + av.x * inv, hv.y + av.y * inv, hv.z + av.z * inv, hv.w + av.w * inv};
    ((float4*)out)[i] = o;
}

// ---------------------------------------------------------------------------
extern "C" void kernel_launch(void* const* d_in, const int* in_sizes, int n_in,
                              void* d_out, int out_size, void* d_ws, size_t ws_size,
                              hipStream_t stream) {
    const float* h   = (const float*)d_in[0];
    const int*   ei  = (const int*)  d_in[1];
    const float* ea  = (const float*)d_in[2];
    const float* We  = (const float*)d_in[3];
    const float* be  = (const float*)d_in[4];
    const float* Wn  = (const float*)d_in[5];
    const float* bn  = (const float*)d_in[6];

    const int N = in_sizes[0] / NODE_DIM;     // 50000
    const int E = in_sizes[2] / EDGE_DIM;     // 800000
    char* ws = (char*)d_ws;

    size_t off = 0;
    auto take = [&](size_t bytes) { size_t o = off; off = (off + bytes + 511) & ~(size_t)511; return o; };
    const size_t O_BPACK = take((size_t)KT_TILES * NT_TILES * 64 * 16);   // 96 KB
    const size_t O_DEG   = take((size_t)N * 4);                           // | memset
    const size_t O_HNEW  = take((size_t)N * NODE_DIM * 4);                // | together
    const size_t O_MEMSET_END = off;
    const size_t O_SCAN  = take((size_t)N * 4);
    const size_t O_BSUM  = take(1024);
    const size_t O_BPREF = take(1024);
    const size_t O_OFFS  = take((size_t)(N + 1) * 4);
    const size_t O_CURS  = take((size_t)N * 4);
    const size_t O_SSE   = take((size_t)E * 8);                           // int2
    const size_t O_SD    = take((size_t)E * 4);
    const size_t O_HB    = take((size_t)N * NODE_DIM * 2);                // 9.6 MB
    (void)ws_size;

    unsigned short* bpack = (unsigned short*)(ws + O_BPACK);
    unsigned* deg   = (unsigned*)(ws + O_DEG);
    float*    hnew  = (float*)(ws + O_HNEW);
    unsigned* scn   = (unsigned*)(ws + O_SCAN);
    unsigned* bsum  = (unsigned*)(ws + O_BSUM);
    unsigned* bpref = (unsigned*)(ws + O_BPREF);
    unsigned* offs  = (unsigned*)(ws + O_OFFS);
    unsigned* curs  = (unsigned*)(ws + O_CURS);
    int2*     s_se  = (int2*)(ws + O_SSE);
    int*      s_d   = (int*)(ws + O_SD);
    unsigned short* hb = (unsigned short*)(ws + O_HB);

    // zero deg + hnew (contiguous)
    hipMemsetAsync(ws + O_DEG, 0, O_MEMSET_END - O_DEG, stream);

    pack_w_kernel<<<(KT_TILES * NT_TILES * 64 + 255) / 256, 256, 0, stream>>>(We, Wn, bpack);

    const int total8 = N * NODE_DIM / 8;   // 600000
    cvt_h_kernel<<<(total8 + 255) / 256, 256, 0, stream>>>(h, hb, total8);

    const int NB = (N + 255) / 256;        // 196
    hist_kernel<<<(E + 255) / 256, 256, 0, stream>>>(ei, deg, E);
    scan_block_kernel<<<NB, 256, 0, stream>>>(deg, scn, bsum, N);
    scan_sums_kernel<<<1, 256, 0, stream>>>(bsum, bpref, NB);
    scan_finalize_kernel<<<NB, 256, 0, stream>>>(scn, bpref, offs, curs, N, E);
    scatter_kernel<<<(E + 255) / 256, 256, 0, stream>>>(ei, curs, s_se, s_d, E);

    gemm_sorted_kernel<<<(E + 127) / 128, 256, 0, stream>>>(hb, s_se, s_d, ea, bpack,
                                                            be, bn, hnew, E);

    const int total4 = N * (NODE_DIM / 4);
    finalize_kernel<<<(total4 + 255) / 256, 256, 0, stream>>>(h, hnew, offs, (float*)d_out, total4);
}